// Round 15
// baseline (917.239 us; speedup 1.0000x reference)
//
#include <hip/hip_runtime.h>
#include <hip/hip_fp8.h>
#include <stdint.h>

#define T_ROWS 1024
#define NVIS   4096
#define NHID   2048
#define KGIBBS 25   // K is a static python int (25) in setup_inputs

typedef __attribute__((ext_vector_type(4))) float f32x4;
typedef __attribute__((ext_vector_type(2))) long long2v;

#define AS1CV(p) ((const __attribute__((address_space(1))) void*)(p))
#define AS3V(p)  ((__attribute__((address_space(3))) void*)(p))

__device__ inline unsigned char f2e4m3(float f) {
  __hip_fp8_e4m3 q(f);               // OCP e4m3fn on gfx950
  return (unsigned char)q.__x;
}

// k-byte permutation within each 64B group (rotate bits [5:3]):
// chunk (16B) index becomes pair*4 + lq so b128 reads match the proven
// bf16 XOR-swizzle pattern. pos[3]=kb[5], pos[5:4]=kb[4:3].
__device__ __host__ inline int permpos(int kb) {
  return (kb & ~63) | (kb & 7) | (((kb >> 5) & 1) << 3) | (((kb >> 3) & 3) << 4);
}
// inverse: kb[5]=pos[3], kb[4:3]=pos[5:4]
__device__ inline int invpos(int pos) {
  return (pos & ~63) | (pos & 7) | (((pos >> 3) & 1) << 5) | (((pos >> 4) & 3) << 3);
}

// deterministic counter-based uniform in [0,1): murmur3 fmix64 of (phase, idx)
__device__ inline float rng_u(uint32_t phase, uint32_t idx) {
  uint64_t z = (((uint64_t)phase) << 42) | (uint64_t)idx;
  z ^= z >> 33; z *= 0xFF51AFD7ED558CCDULL;
  z ^= z >> 33; z *= 0xC4CEB9FE1A85EC53ULL;
  z ^= z >> 33;
  return (float)(uint32_t)(z >> 40) * (1.0f / 16777216.0f);
}

// ---------------------------------------------------------------------------
// W prep: fp32 -> W8 = e4m3(w*64) [NH][NV] and WT8 [NV][NH], k-permuted.
// ---------------------------------------------------------------------------
__global__ void __launch_bounds__(256) prep_w8(const float* __restrict__ w,
                                               unsigned char* __restrict__ W8,
                                               unsigned char* __restrict__ WT8)
{
  __shared__ unsigned char t8[64][68];
  const int bi  = blockIdx.x * 64;   // NV offset
  const int bh0 = blockIdx.y * 64;   // NH offset
  const int t   = threadIdx.x;
  const int rr  = t >> 4;            // 0..15
  const int cc  = (t & 15) * 4;      // 0,4,..,60
  const int pcc = permpos(cc);       // 4-aligned (bits 1:0 preserved)
#pragma unroll
  for (int p = 0; p < 4; ++p) {
    int row = p * 16 + rr;
    const float4 v = *(const float4*)&w[(size_t)(bh0 + row) * NVIS + bi + cc];
    unsigned char b0 = f2e4m3(v.x * 64.f), b1 = f2e4m3(v.y * 64.f);
    unsigned char b2 = f2e4m3(v.z * 64.f), b3 = f2e4m3(v.w * 64.f);
    uint32_t pk = (uint32_t)b0 | ((uint32_t)b1 << 8) |
                  ((uint32_t)b2 << 16) | ((uint32_t)b3 << 24);
    *(uint32_t*)&W8[(size_t)(bh0 + row) * NVIS + bi + pcc] = pk;
    t8[cc + 0][row] = b0; t8[cc + 1][row] = b1;
    t8[cc + 2][row] = b2; t8[cc + 3][row] = b3;
  }
  __syncthreads();
#pragma unroll
  for (int p = 0; p < 4; ++p) {
    int irow = p * 16 + rr;          // NV-local
    uint32_t o = (uint32_t)t8[irow][cc + 0] | ((uint32_t)t8[irow][cc + 1] << 8) |
                 ((uint32_t)t8[irow][cc + 2] << 16) | ((uint32_t)t8[irow][cc + 3] << 24);
    *(uint32_t*)&WT8[(size_t)(bi + irow) * NHID + bh0 + pcc] = o;
  }
}

// x (fp32 0/1) -> fp8 V8 (k-permuted positions)
__global__ void __launch_bounds__(256) xcvt8(const float* __restrict__ x,
                                             unsigned char* __restrict__ V8)
{
  int i = blockIdx.x * 256 + threadIdx.x;
  const float4 v = ((const float4*)x)[i];
  uint32_t p8 = (uint32_t)f2e4m3(v.x) | ((uint32_t)f2e4m3(v.y) << 8) |
                ((uint32_t)f2e4m3(v.z) << 16) | ((uint32_t)f2e4m3(v.w) << 24);
  int o = i * 4;                       // global byte offset (rows 4096-aligned)
  *(uint32_t*)&V8[(o & ~63) | (permpos(o & 63))] = p8;
}

// sum over (t,i) of x[t,i]*bv[i], x fp32 -> 256 partials
__global__ void __launch_bounds__(256) bvdot_x(const float* __restrict__ x,
                                               const float* __restrict__ bv,
                                               float* __restrict__ part)
{
  float local = 0.f;
  for (int i = blockIdx.x * 256 + threadIdx.x; i < T_ROWS * NVIS / 4; i += 256 * 256) {
    int col4 = (i & (NVIS / 4 - 1)) * 4;
    const float4 a = ((const float4*)x)[i];
    const float4 b = *(const float4*)&bv[col4];
    local += a.x * b.x + a.y * b.y + a.z * b.z + a.w * b.w;
  }
#pragma unroll
  for (int off = 32; off > 0; off >>= 1) local += __shfl_down(local, off, 64);
  __shared__ float red[4];
  if ((threadIdx.x & 63) == 0) red[threadIdx.x >> 6] = local;
  __syncthreads();
  if (threadIdx.x == 0) part[blockIdx.x] = red[0] + red[1] + red[2] + red[3];
}

// sum over (t,i) of v8[t,i]*bv[i]; V8 is k-permuted e4m3 {0, 0x38=1.0}
__global__ void __launch_bounds__(256) bvdot8(const unsigned char* __restrict__ V8,
                                              const float* __restrict__ bv,
                                              float* __restrict__ part)
{
  float local = 0.f;
  for (int i = blockIdx.x * 256 + threadIdx.x; i < T_ROWS * NVIS / 4; i += 256 * 256) {
    int o = (i * 4) & (NVIS - 1);              // within-row storage offset
    int col4 = (o & ~63) | invpos(o & 63);     // original col base (4-aligned)
    uint32_t b = ((const uint32_t*)V8)[i];
    const float4 bvv = *(const float4*)&bv[col4];
    if (((b >> 0)  & 0xFF) == 0x38) local += bvv.x;
    if (((b >> 8)  & 0xFF) == 0x38) local += bvv.y;
    if (((b >> 16) & 0xFF) == 0x38) local += bvv.z;
    if (((b >> 24) & 0xFF) == 0x38) local += bvv.w;
  }
#pragma unroll
  for (int off = 32; off > 0; off >>= 1) local += __shfl_down(local, off, 64);
  __shared__ float red[4];
  if ((threadIdx.x & 63) == 0) red[threadIdx.x >> 6] = local;
  __syncthreads();
  if (threadIdx.x == 0) part[blockIdx.x] = red[0] + red[1] + red[2] + red[3];
}

// ---------------------------------------------------------------------------
// fp8 chain GEMM, BK=128, k-permuted operands, b128 fragment reads with the
// proven (chunk = pair*4+lq) ^ (row&7) swizzle -> conflict-free.
// 256 threads = 4 waves in 2M x 2N (wave tile 32 x BN/2): read:MFMA ratio
// halves vs the 8-wave shape (LDS-throughput was the measured wall).
// BM=64; BN=64 (H, 48KB LDS, 3 blocks/CU) or 128 (V, 72KB, 2 blocks/CU);
// grid 512 blocks. 16x16x32 fp8 MFMA. z = acc/64 + bias.
// MODE 0: sample -> C8.  MODE 1: sample + softplus partials.  MODE 2: partials.
// ---------------------------------------------------------------------------
template <int BN, int MODE>
__global__ void __launch_bounds__(256, (BN == 64) ? 3 : 2)
rbm_gemm8(const unsigned char* __restrict__ A, int lda,
          const unsigned char* __restrict__ B, int ldb,
          const float* __restrict__ bias,
          unsigned char* __restrict__ C8, int ldc,
          float* __restrict__ fpart,
          int kdim, uint32_t phase)
{
  constexpr int BM = 64;
  constexpr int BK = 128;               // 8 x 16B chunks per row
  constexpr int MR = 2;                 // 32 rows / 16
  constexpr int NR = BN / 32;           // 2 (H) or 4 (V): wave tile 32 x BN/2
  constexpr int ABYTES = BM * BK;       // 8 KB
  constexpr int BBYTES = BN * BK;       // 8 or 16 KB
  constexpr int BUFB = ABYTES + BBYTES; // 16 or 24 KB
  constexpr int AJ = 2;                 // 8KB / (256 thr * 16B)
  constexpr int BJ = BBYTES / 4096;     // 2 or 4
  constexpr int NL = AJ + BJ;           // 4 or 6
  __shared__ __align__(16) char lds[3 * BUFB];

  const int tid  = threadIdx.x;
  const int lane = tid & 63;
  const int wv   = tid >> 6;            // 0..3
  const int wr   = wv >> 1;             // 0..1 (M)
  const int wc   = wv & 1;              // 0..1 (N)
  const int lr   = lane & 15;
  const int lq   = lane >> 4;           // 0..3

  // XCD-chunked tile swizzle (nb % 8 == 0 -> bijective)
  const int gy = gridDim.y;             // 16
  const int nb = gridDim.x * gy;        // 512
  int orig = blockIdx.x + blockIdx.y * gridDim.x;
  int id = (orig & 7) * (nb >> 3) + (orig >> 3);
  int tx = id / gy;
  int ty = id - tx * gy;
  const int bm0 = ty * BM;
  const int bn0 = tx * BN;

  // staging: chunk L = j*256+tid -> row = L>>3, slot = L&7; j adds 32 rows
  // source chunk = slot ^ (row&7); j-invariant (32 % 8 == 0).
  const int sRow = tid >> 3;            // 0..31
  const int sCol = (((tid & 7) ^ (sRow & 7)) * 16);
  const unsigned char* gA = A + (size_t)(bm0 + sRow) * lda + sCol;
  const unsigned char* gB = B + (size_t)(bn0 + sRow) * ldb + sCol;

  auto STAGE = [&](int buf, int kt) {
    char* base = lds + buf * BUFB;
    const unsigned char* a0 = gA + (size_t)kt * BK;
    const unsigned char* b0 = gB + (size_t)kt * BK;
#pragma unroll
    for (int j = 0; j < AJ; ++j)
      __builtin_amdgcn_global_load_lds(AS1CV(a0 + (size_t)j * 32 * lda),
                                       AS3V(base + (j * 256 + tid) * 16), 16, 0, 0);
    char* bb = base + ABYTES;
#pragma unroll
    for (int j = 0; j < BJ; ++j)
      __builtin_amdgcn_global_load_lds(AS1CV(b0 + (size_t)j * 32 * ldb),
                                       AS3V(bb + (j * 256 + tid) * 16), 16, 0, 0);
  };

  f32x4 acc[MR][NR];
#pragma unroll
  for (int m = 0; m < MR; ++m)
#pragma unroll
    for (int n = 0; n < NR; ++n) acc[m][n] = (f32x4)0.0f;

  const int nkt = kdim / BK;            // 32 (H) or 16 (V)
  STAGE(0, 0);

  int cur = 0;
  for (int kt = 0; kt < nkt; ++kt) {
    int nxt = (cur == 2) ? 0 : cur + 1;
    if (kt + 1 < nkt) {
      STAGE(nxt, kt + 1);
      if constexpr (NL == 4) asm volatile("s_waitcnt vmcnt(4)" ::: "memory");
      else                   asm volatile("s_waitcnt vmcnt(6)" ::: "memory");
    } else {
      asm volatile("s_waitcnt vmcnt(0)" ::: "memory");
    }
    __builtin_amdgcn_sched_barrier(0);
    __builtin_amdgcn_s_barrier();
    __builtin_amdgcn_sched_barrier(0);

    char* base = lds + cur * BUFB;
    char* bb = base + ABYTES;
#pragma unroll
    for (int p = 0; p < 2; ++p) {             // slice pairs (2 slices each)
      long2v afv[MR], bfv[NR];
      const int chunk = p * 4 + lq;           // 16B chunk: slice2p|slice2p+1 for lq
#pragma unroll
      for (int m = 0; m < MR; ++m) {
        int row = wr * 32 + m * 16 + lr;
        afv[m] = *(const long2v*)(base + row * BK + ((chunk ^ (row & 7)) * 16));
      }
#pragma unroll
      for (int n = 0; n < NR; ++n) {
        int row = wc * (BN / 2) + n * 16 + lr;
        bfv[n] = *(const long2v*)(bb + row * BK + ((chunk ^ (row & 7)) * 16));
      }
      __builtin_amdgcn_s_setprio(1);
#pragma unroll
      for (int m = 0; m < MR; ++m)
#pragma unroll
        for (int n = 0; n < NR; ++n)
          acc[m][n] = __builtin_amdgcn_mfma_f32_16x16x32_fp8_fp8(afv[m].x, bfv[n].x, acc[m][n], 0, 0, 0);
#pragma unroll
      for (int m = 0; m < MR; ++m)
#pragma unroll
        for (int n = 0; n < NR; ++n)
          acc[m][n] = __builtin_amdgcn_mfma_f32_16x16x32_fp8_fp8(afv[m].y, bfv[n].y, acc[m][n], 0, 0, 0);
      __builtin_amdgcn_s_setprio(0);
    }
    cur = nxt;
  }

  // epilogue: z = acc/64 + bias; sample writes go to k-permuted positions
  float local = 0.0f;
#pragma unroll
  for (int n = 0; n < NR; ++n) {
    int col = bn0 + wc * (BN / 2) + n * 16 + lr;
    float bv_ = bias[col];
    int pcol = (col & ~63) | (col & 7) | (((col >> 5) & 1) << 3) | (((col >> 3) & 3) << 4);
#pragma unroll
    for (int m = 0; m < MR; ++m) {
      int row0 = bm0 + wr * 32 + m * 16 + lq * 4;
#pragma unroll
      for (int j = 0; j < 4; ++j) {
        int row = row0 + j;
        float z = acc[m][n][j] * 0.015625f + bv_;
        if (MODE != 2) {
          float p = 1.0f / (1.0f + __expf(-z));
          float u = rng_u(phase, (uint32_t)(row * ldc + col));
          C8[(size_t)row * ldc + pcol] = (u < p) ? (unsigned char)0x38 : (unsigned char)0;
        }
        if (MODE != 0)
          local += fmaxf(z, 0.0f) + log1pf(expf(-fabsf(z)));
      }
    }
  }

  if (MODE != 0) {
#pragma unroll
    for (int off = 32; off > 0; off >>= 1) local += __shfl_down(local, off, 64);
    float* red = (float*)lds;
    __syncthreads();
    if (lane == 0) red[wv] = local;
    __syncthreads();
    if (tid == 0)
      fpart[id] = red[0] + red[1] + red[2] + red[3];
  }
}

// cost = (Sv + v.bv - Sx - x.bv) / T, double-precision reduce
// pFx[512], pFv[512], pXbv[256], pVbv[256]
__global__ void __launch_bounds__(256) finalize(const float* __restrict__ pFx,
                                                const float* __restrict__ pFv,
                                                const float* __restrict__ pXbv,
                                                const float* __restrict__ pVbv,
                                                float* __restrict__ out)
{
  __shared__ double red[256];
  double local = 0.0;
  int t = threadIdx.x;
  for (int i = t; i < 1536; i += 256) {
    if (i < 512)       local -= (double)pFx[i];
    else if (i < 1024) local += (double)pFv[i - 512];
    else if (i < 1280) local -= (double)pXbv[i - 1024];
    else               local += (double)pVbv[i - 1280];
  }
  red[t] = local;
  __syncthreads();
  for (int s = 128; s > 0; s >>= 1) {
    if (t < s) red[t] += red[t + s];
    __syncthreads();
  }
  if (t == 0) out[0] = (float)(red[0] / (double)T_ROWS);
}

extern "C" void kernel_launch(void* const* d_in, const int* in_sizes, int n_in,
                              void* d_out, int out_size, void* d_ws, size_t ws_size,
                              hipStream_t stream)
{
  const float* x  = (const float*)d_in[0];
  const float* w  = (const float*)d_in[1];
  const float* bh = (const float*)d_in[2];
  const float* bv = (const float*)d_in[3];

  char* ws = (char*)d_ws;
  unsigned char* W8  = (unsigned char*)ws;                          //  8 MB
  unsigned char* WT8 = (unsigned char*)(ws + (size_t)8388608);      //  8 MB
  unsigned char* V8  = (unsigned char*)(ws + (size_t)16777216);     //  4 MB
  unsigned char* H8  = (unsigned char*)(ws + (size_t)20971520);     //  2 MB
  float* pFx  = (float*)(ws + (size_t)23068672);
  float* pFv  = pFx + 512;
  float* pXbv = pFv + 512;
  float* pVbv = pXbv + 256;

  prep_w8<<<dim3(NVIS / 64, NHID / 64), 256, 0, stream>>>(w, W8, WT8);
  xcvt8<<<(T_ROWS * NVIS / 4) / 256, 256, 0, stream>>>(x, V8);
  bvdot_x<<<256, 256, 0, stream>>>(x, bv, pXbv);

  // chain; H-step k=0 doubles as F(x) (same z, phase 0)
  for (int k = 0; k < KGIBBS; ++k) {
    if (k == 0)
      rbm_gemm8<64, 1><<<dim3(NHID / 64, T_ROWS / 64), 256, 0, stream>>>(
          V8, NVIS, W8, NVIS, bh, H8, NHID, pFx, NVIS, 0u);
    else
      rbm_gemm8<64, 0><<<dim3(NHID / 64, T_ROWS / 64), 256, 0, stream>>>(
          V8, NVIS, W8, NVIS, bh, H8, NHID, nullptr, NVIS, (uint32_t)(2 * k));
    rbm_gemm8<128, 0><<<dim3(NVIS / 128, T_ROWS / 64), 256, 0, stream>>>(
        H8, NHID, WT8, NHID, bv, V8, NVIS, nullptr, NHID, (uint32_t)(2 * k + 1));
  }

  // F(v_o): one extra H-shaped pass, softplus partials only
  rbm_gemm8<64, 2><<<dim3(NHID / 64, T_ROWS / 64), 256, 0, stream>>>(
      V8, NVIS, W8, NVIS, bh, nullptr, NHID, pFv, NVIS, 0u);
  bvdot8<<<256, 256, 0, stream>>>(V8, bv, pVbv);

  finalize<<<1, 256, 0, stream>>>(pFx, pFv, pXbv, pVbv, (float*)d_out);
}

// Round 16
// 877.986 us; speedup vs baseline: 1.0447x; 1.0447x over previous
//
#include <hip/hip_runtime.h>
#include <hip/hip_fp8.h>
#include <stdint.h>

#define T_ROWS 1024
#define NVIS   4096
#define NHID   2048
#define KGIBBS 25   // K is a static python int (25) in setup_inputs

typedef __attribute__((ext_vector_type(4))) float f32x4;
typedef __attribute__((ext_vector_type(2))) long long2v;

#define AS1CV(p) ((const __attribute__((address_space(1))) void*)(p))
#define AS3V(p)  ((__attribute__((address_space(3))) void*)(p))

__device__ inline unsigned char f2e4m3(float f) {
  __hip_fp8_e4m3 q(f);               // OCP e4m3fn on gfx950
  return (unsigned char)q.__x;
}

// k-byte permutation within each 64B group (rotate bits [5:3]):
// chunk (16B) index becomes pair*4 + lq so b128 reads match the proven
// bf16 XOR-swizzle pattern. pos[3]=kb[5], pos[5:4]=kb[4:3].
__device__ __host__ inline int permpos(int kb) {
  return (kb & ~63) | (kb & 7) | (((kb >> 5) & 1) << 3) | (((kb >> 3) & 3) << 4);
}
// inverse: kb[5]=pos[3], kb[4:3]=pos[5:4]
__device__ inline int invpos(int pos) {
  return (pos & ~63) | (pos & 7) | (((pos >> 3) & 1) << 5) | (((pos >> 4) & 3) << 3);
}

// deterministic counter-based uniform in [0,1): murmur3 fmix64 of (phase, idx)
__device__ inline float rng_u(uint32_t phase, uint32_t idx) {
  uint64_t z = (((uint64_t)phase) << 42) | (uint64_t)idx;
  z ^= z >> 33; z *= 0xFF51AFD7ED558CCDULL;
  z ^= z >> 33; z *= 0xC4CEB9FE1A85EC53ULL;
  z ^= z >> 33;
  return (float)(uint32_t)(z >> 40) * (1.0f / 16777216.0f);
}

// ---------------------------------------------------------------------------
// W prep: fp32 -> W8 = e4m3(w*64) [NH][NV] and WT8 [NV][NH], k-permuted.
// ---------------------------------------------------------------------------
__global__ void __launch_bounds__(256) prep_w8(const float* __restrict__ w,
                                               unsigned char* __restrict__ W8,
                                               unsigned char* __restrict__ WT8)
{
  __shared__ unsigned char t8[64][68];
  const int bi  = blockIdx.x * 64;   // NV offset
  const int bh0 = blockIdx.y * 64;   // NH offset
  const int t   = threadIdx.x;
  const int rr  = t >> 4;            // 0..15
  const int cc  = (t & 15) * 4;      // 0,4,..,60
  const int pcc = permpos(cc);       // 4-aligned (bits 1:0 preserved)
#pragma unroll
  for (int p = 0; p < 4; ++p) {
    int row = p * 16 + rr;
    const float4 v = *(const float4*)&w[(size_t)(bh0 + row) * NVIS + bi + cc];
    unsigned char b0 = f2e4m3(v.x * 64.f), b1 = f2e4m3(v.y * 64.f);
    unsigned char b2 = f2e4m3(v.z * 64.f), b3 = f2e4m3(v.w * 64.f);
    uint32_t pk = (uint32_t)b0 | ((uint32_t)b1 << 8) |
                  ((uint32_t)b2 << 16) | ((uint32_t)b3 << 24);
    *(uint32_t*)&W8[(size_t)(bh0 + row) * NVIS + bi + pcc] = pk;
    t8[cc + 0][row] = b0; t8[cc + 1][row] = b1;
    t8[cc + 2][row] = b2; t8[cc + 3][row] = b3;
  }
  __syncthreads();
#pragma unroll
  for (int p = 0; p < 4; ++p) {
    int irow = p * 16 + rr;          // NV-local
    uint32_t o = (uint32_t)t8[irow][cc + 0] | ((uint32_t)t8[irow][cc + 1] << 8) |
                 ((uint32_t)t8[irow][cc + 2] << 16) | ((uint32_t)t8[irow][cc + 3] << 24);
    *(uint32_t*)&WT8[(size_t)(bi + irow) * NHID + bh0 + pcc] = o;
  }
}

// x (fp32 0/1) -> fp8 V8 (k-permuted positions), fused with x.bv partials
__global__ void __launch_bounds__(256) xcvt8(const float* __restrict__ x,
                                             const float* __restrict__ bv,
                                             unsigned char* __restrict__ V8,
                                             float* __restrict__ part)
{
  float local = 0.f;
  for (int i = blockIdx.x * 256 + threadIdx.x; i < T_ROWS * NVIS / 4; i += 256 * 256) {
    const float4 v = ((const float4*)x)[i];
    uint32_t p8 = (uint32_t)f2e4m3(v.x) | ((uint32_t)f2e4m3(v.y) << 8) |
                  ((uint32_t)f2e4m3(v.z) << 16) | ((uint32_t)f2e4m3(v.w) << 24);
    int o = i * 4;                     // global byte offset (rows 4096-aligned)
    *(uint32_t*)&V8[(o & ~63) | (permpos(o & 63))] = p8;
    int col4 = (i & (NVIS / 4 - 1)) * 4;
    const float4 b = *(const float4*)&bv[col4];
    local += v.x * b.x + v.y * b.y + v.z * b.z + v.w * b.w;
  }
#pragma unroll
  for (int off = 32; off > 0; off >>= 1) local += __shfl_down(local, off, 64);
  __shared__ float red[4];
  if ((threadIdx.x & 63) == 0) red[threadIdx.x >> 6] = local;
  __syncthreads();
  if (threadIdx.x == 0) part[blockIdx.x] = red[0] + red[1] + red[2] + red[3];
}

// sum over (t,i) of v8[t,i]*bv[i]; V8 is k-permuted e4m3 {0, 0x38=1.0}
__global__ void __launch_bounds__(256) bvdot8(const unsigned char* __restrict__ V8,
                                              const float* __restrict__ bv,
                                              float* __restrict__ part)
{
  float local = 0.f;
  for (int i = blockIdx.x * 256 + threadIdx.x; i < T_ROWS * NVIS / 4; i += 256 * 256) {
    int o = (i * 4) & (NVIS - 1);              // within-row storage offset
    int col4 = (o & ~63) | invpos(o & 63);     // original col base (4-aligned)
    uint32_t b = ((const uint32_t*)V8)[i];
    const float4 bvv = *(const float4*)&bv[col4];
    if (((b >> 0)  & 0xFF) == 0x38) local += bvv.x;
    if (((b >> 8)  & 0xFF) == 0x38) local += bvv.y;
    if (((b >> 16) & 0xFF) == 0x38) local += bvv.z;
    if (((b >> 24) & 0xFF) == 0x38) local += bvv.w;
  }
#pragma unroll
  for (int off = 32; off > 0; off >>= 1) local += __shfl_down(local, off, 64);
  __shared__ float red[4];
  if ((threadIdx.x & 63) == 0) red[threadIdx.x >> 6] = local;
  __syncthreads();
  if (threadIdx.x == 0) part[blockIdx.x] = red[0] + red[1] + red[2] + red[3];
}

// ---------------------------------------------------------------------------
// fp8 chain GEMM, BK=128, k-permuted operands, b128 fragment reads with the
// proven (chunk = pair*4+lq) ^ (row&7) swizzle -> conflict-free (R12 config).
// C[M,N] = A[M,K]*B^T (B stored [N][K]); z = acc/64 + bias.
// BM=64; BN=64 (H) or 128 (V); grid 512 blocks -> 2-3 blocks/CU.
// 512 thr = 8 waves (2M x 4N), 16x16x32 fp8 MFMA.
// MODE 0: sample -> C8.  MODE 1: sample + softplus partials.  MODE 2: partials.
// ---------------------------------------------------------------------------
template <int BN, int MODE>
__global__ void __launch_bounds__(512, 4)
rbm_gemm8(const unsigned char* __restrict__ A, int lda,
          const unsigned char* __restrict__ B, int ldb,
          const float* __restrict__ bias,
          unsigned char* __restrict__ C8, int ldc,
          float* __restrict__ fpart,
          int kdim, uint32_t phase)
{
  constexpr int BM = 64;
  constexpr int BK = 128;               // 8 x 16B chunks per row
  constexpr int MR = 2;                 // BM/32
  constexpr int NR = BN / 64;           // 1 or 2
  constexpr int ABYTES = BM * BK;       // 8 KB
  constexpr int BBYTES = BN * BK;       // 8 or 16 KB
  constexpr int BUFB = ABYTES + BBYTES; // 16 or 24 KB
  constexpr int AJ = 1;
  constexpr int BJ = BBYTES / 8192;     // 1 or 2
  constexpr int NL = AJ + BJ;           // 2 or 3
  __shared__ __align__(16) char lds[3 * BUFB];

  const int tid  = threadIdx.x;
  const int lane = tid & 63;
  const int wv   = tid >> 6;
  const int wr   = wv >> 2;             // 0..1 (M)
  const int wc   = wv & 3;              // 0..3 (N)
  const int lr   = lane & 15;
  const int lq   = lane >> 4;           // 0..3

  // XCD-chunked tile swizzle (nb % 8 == 0 -> bijective)
  const int gy = gridDim.y;             // 16
  const int nb = gridDim.x * gy;        // 512
  int orig = blockIdx.x + blockIdx.y * gridDim.x;
  int id = (orig & 7) * (nb >> 3) + (orig >> 3);
  int tx = id / gy;
  int ty = id - tx * gy;
  const int bm0 = ty * BM;
  const int bn0 = tx * BN;

  // staging: chunk L = j*512+tid -> row = L>>3, slot = L&7;
  // source chunk = slot ^ (row&7); j-invariant (j adds 64 rows).
  const int sRow = tid >> 3;            // 0..63
  const int sCol = (((tid & 7) ^ (sRow & 7)) * 16);
  const unsigned char* gA = A + (size_t)(bm0 + sRow) * lda + sCol;
  const unsigned char* gB = B + (size_t)(bn0 + sRow) * ldb + sCol;

  auto STAGE = [&](int buf, int kt) {
    char* base = lds + buf * BUFB;
    const unsigned char* a0 = gA + (size_t)kt * BK;
    const unsigned char* b0 = gB + (size_t)kt * BK;
    __builtin_amdgcn_global_load_lds(AS1CV(a0), AS3V(base + tid * 16), 16, 0, 0);
    char* bb = base + ABYTES;
#pragma unroll
    for (int j = 0; j < BJ; ++j)
      __builtin_amdgcn_global_load_lds(AS1CV(b0 + (size_t)j * 64 * ldb),
                                       AS3V(bb + (j * 512 + tid) * 16), 16, 0, 0);
  };

  f32x4 acc[MR][NR];
#pragma unroll
  for (int m = 0; m < MR; ++m)
#pragma unroll
    for (int n = 0; n < NR; ++n) acc[m][n] = (f32x4)0.0f;

  const int nkt = kdim / BK;            // 32 (H) or 16 (V)
  STAGE(0, 0);

  int cur = 0;
  for (int kt = 0; kt < nkt; ++kt) {
    int nxt = (cur == 2) ? 0 : cur + 1;
    if (kt + 1 < nkt) {
      STAGE(nxt, kt + 1);
      if constexpr (NL == 2) asm volatile("s_waitcnt vmcnt(2)" ::: "memory");
      else                   asm volatile("s_waitcnt vmcnt(3)" ::: "memory");
    } else {
      asm volatile("s_waitcnt vmcnt(0)" ::: "memory");
    }
    __builtin_amdgcn_sched_barrier(0);
    __builtin_amdgcn_s_barrier();
    __builtin_amdgcn_sched_barrier(0);

    char* base = lds + cur * BUFB;
    char* bb = base + ABYTES;
#pragma unroll
    for (int p = 0; p < 2; ++p) {             // slice pairs (2 slices each)
      long2v afv[MR], bfv[NR];
      const int chunk = p * 4 + lq;           // 16B chunk: slice2p|slice2p+1 for lq
#pragma unroll
      for (int m = 0; m < MR; ++m) {
        int row = wr * 32 + m * 16 + lr;
        afv[m] = *(const long2v*)(base + row * BK + ((chunk ^ (row & 7)) * 16));
      }
#pragma unroll
      for (int n = 0; n < NR; ++n) {
        int row = wc * (BN / 4) + n * 16 + lr;
        bfv[n] = *(const long2v*)(bb + row * BK + ((chunk ^ (row & 7)) * 16));
      }
#pragma unroll
      for (int m = 0; m < MR; ++m)
#pragma unroll
        for (int n = 0; n < NR; ++n)
          acc[m][n] = __builtin_amdgcn_mfma_f32_16x16x32_fp8_fp8(afv[m].x, bfv[n].x, acc[m][n], 0, 0, 0);
#pragma unroll
      for (int m = 0; m < MR; ++m)
#pragma unroll
        for (int n = 0; n < NR; ++n)
          acc[m][n] = __builtin_amdgcn_mfma_f32_16x16x32_fp8_fp8(afv[m].y, bfv[n].y, acc[m][n], 0, 0, 0);
    }
    cur = nxt;
  }

  // epilogue: z = acc/64 + bias; sample writes go to k-permuted positions
  float local = 0.0f;
#pragma unroll
  for (int n = 0; n < NR; ++n) {
    int col = bn0 + wc * (BN / 4) + n * 16 + lr;
    float bv_ = bias[col];
    int pcol = (col & ~63) | (col & 7) | (((col >> 5) & 1) << 3) | (((col >> 3) & 3) << 4);
#pragma unroll
    for (int m = 0; m < MR; ++m) {
      int row0 = bm0 + wr * 32 + m * 16 + lq * 4;
#pragma unroll
      for (int j = 0; j < 4; ++j) {
        int row = row0 + j;
        float z = acc[m][n][j] * 0.015625f + bv_;
        if (MODE != 2) {
          float p = 1.0f / (1.0f + __expf(-z));
          float u = rng_u(phase, (uint32_t)(row * ldc + col));
          C8[(size_t)row * ldc + pcol] = (u < p) ? (unsigned char)0x38 : (unsigned char)0;
        }
        if (MODE != 0)
          local += fmaxf(z, 0.0f) + log1pf(expf(-fabsf(z)));
      }
    }
  }

  if (MODE != 0) {
#pragma unroll
    for (int off = 32; off > 0; off >>= 1) local += __shfl_down(local, off, 64);
    float* red = (float*)lds;
    __syncthreads();
    if (lane == 0) red[wv] = local;
    __syncthreads();
    if (tid == 0)
      fpart[id] = red[0] + red[1] + red[2] + red[3] + red[4] + red[5] + red[6] + red[7];
  }
}

// cost = (Sv + v.bv - Sx - x.bv) / T, double-precision reduce
// pFx[512], pFv[512], pXbv[256], pVbv[256]
__global__ void __launch_bounds__(256) finalize(const float* __restrict__ pFx,
                                                const float* __restrict__ pFv,
                                                const float* __restrict__ pXbv,
                                                const float* __restrict__ pVbv,
                                                float* __restrict__ out)
{
  __shared__ double red[256];
  double local = 0.0;
  int t = threadIdx.x;
  for (int i = t; i < 1536; i += 256) {
    if (i < 512)       local -= (double)pFx[i];
    else if (i < 1024) local += (double)pFv[i - 512];
    else if (i < 1280) local -= (double)pXbv[i - 1024];
    else               local += (double)pVbv[i - 1280];
  }
  red[t] = local;
  __syncthreads();
  for (int s = 128; s > 0; s >>= 1) {
    if (t < s) red[t] += red[t + s];
    __syncthreads();
  }
  if (t == 0) out[0] = (float)(red[0] / (double)T_ROWS);
}

extern "C" void kernel_launch(void* const* d_in, const int* in_sizes, int n_in,
                              void* d_out, int out_size, void* d_ws, size_t ws_size,
                              hipStream_t stream)
{
  const float* x  = (const float*)d_in[0];
  const float* w  = (const float*)d_in[1];
  const float* bh = (const float*)d_in[2];
  const float* bv = (const float*)d_in[3];

  char* ws = (char*)d_ws;
  unsigned char* W8  = (unsigned char*)ws;                          //  8 MB
  unsigned char* WT8 = (unsigned char*)(ws + (size_t)8388608);      //  8 MB
  unsigned char* V8  = (unsigned char*)(ws + (size_t)16777216);     //  4 MB
  unsigned char* H8  = (unsigned char*)(ws + (size_t)20971520);     //  2 MB
  float* pFx  = (float*)(ws + (size_t)23068672);
  float* pFv  = pFx + 512;
  float* pXbv = pFv + 512;
  float* pVbv = pXbv + 256;

  prep_w8<<<dim3(NVIS / 64, NHID / 64), 256, 0, stream>>>(w, W8, WT8);
  xcvt8<<<256, 256, 0, stream>>>(x, bv, V8, pXbv);

  // chain; H-step k=0 doubles as F(x) (same z, phase 0)
  for (int k = 0; k < KGIBBS; ++k) {
    if (k == 0)
      rbm_gemm8<64, 1><<<dim3(NHID / 64, T_ROWS / 64), 512, 0, stream>>>(
          V8, NVIS, W8, NVIS, bh, H8, NHID, pFx, NVIS, 0u);
    else
      rbm_gemm8<64, 0><<<dim3(NHID / 64, T_ROWS / 64), 512, 0, stream>>>(
          V8, NVIS, W8, NVIS, bh, H8, NHID, nullptr, NVIS, (uint32_t)(2 * k));
    rbm_gemm8<128, 0><<<dim3(NVIS / 128, T_ROWS / 64), 512, 0, stream>>>(
        H8, NHID, WT8, NHID, bv, V8, NVIS, nullptr, NHID, (uint32_t)(2 * k + 1));
  }

  // F(v_o): one extra H-shaped pass, softplus partials only
  rbm_gemm8<64, 2><<<dim3(NHID / 64, T_ROWS / 64), 512, 0, stream>>>(
      V8, NVIS, W8, NVIS, bh, nullptr, NHID, pFv, NVIS, 0u);
  bvdot8<<<256, 256, 0, stream>>>(V8, bv, pVbv);

  finalize<<<1, 256, 0, stream>>>(pFx, pFv, pXbv, pVbv, (float*)d_out);
}